// Round 12
// baseline (490.992 us; speedup 1.0000x reference)
//
#include <hip/hip_runtime.h>
#include <cstdint>
#include <cstddef>

#define DEVI __device__ __forceinline__

typedef __attribute__((ext_vector_type(8))) short bf16x8;
typedef __attribute__((ext_vector_type(4))) float f32x4;

DEVI unsigned short f2bf(float f) {
  unsigned int u = __float_as_uint(f);
  u += 0x7fffu + ((u >> 16) & 1u);   // RNE
  return (unsigned short)(u >> 16);
}
DEVI float bf2f(unsigned int us) { return __uint_as_float(us << 16); }

DEVI void gld_lds16(const void* g, void* l) {
  __builtin_amdgcn_global_load_lds(
      (const __attribute__((address_space(1))) void*)g,
      (__attribute__((address_space(3))) void*)l, 16, 0, 0);
}

// ---------------- fp32 -> bf16 elementwise ----------------
__global__ __launch_bounds__(256) void k_conv(const float* __restrict__ in,
                                              short* __restrict__ out, int n4) {
  int i = blockIdx.x * 256 + threadIdx.x;
  if (i >= n4) return;
  float4 v = reinterpret_cast<const float4*>(in)[i];
  uint2 o;
  o.x = (unsigned)f2bf(v.x) | ((unsigned)f2bf(v.y) << 16);
  o.y = (unsigned)f2bf(v.z) | ((unsigned)f2bf(v.w) << 16);
  reinterpret_cast<uint2*>(out)[i] = o;
}

// ---------------- fp32 [R][C] -> bf16 [C][R] transpose ----------------
__global__ __launch_bounds__(256) void k_transpose(const float* __restrict__ in,
                                                   short* __restrict__ out,
                                                   int R, int Cc) {
  __shared__ short tile[64][66];
  int tcols = Cc >> 6;
  int tb = blockIdx.x % tcols;
  int rb = blockIdx.x / tcols;
  int tid = threadIdx.x;
#pragma unroll
  for (int rep = 0; rep < 16; ++rep) {
    int idx = rep * 256 + tid;
    int r = idx >> 6, c = idx & 63;
    tile[r][c] = (short)f2bf(in[(size_t)(rb * 64 + r) * Cc + tb * 64 + c]);
  }
  __syncthreads();
#pragma unroll
  for (int rep = 0; rep < 16; ++rep) {
    int idx = rep * 256 + tid;
    int r = idx >> 6, c = idx & 63;
    out[(size_t)(tb * 64 + r) * R + rb * 64 + c] = tile[c][r];
  }
}

// ---------------- bf16 GEMM, B^T input (round-4 pipeline, proven) ---------
// BM=BN=256, BK=32, 512 thr (8 waves 2Mx4N), 4 LDS buffers (128KB).
// Staging 3 K-tiles ahead; one counted vmcnt(4) + one s_barrier per tile.
// Register frag double-buffer. 2D grid.
// MODE 1: plain fp32 C.  MODE 2: fused QKV epilogue (RoPE'd Q,K + V^T).
template <int MODE, typename OutT>
__global__ __launch_bounds__(512, 2) void k_gemm8(const short* __restrict__ A,
                                                  const short* __restrict__ BT,
                                                  OutT* __restrict__ C,
                                                  int M, int N, int K,
                                                  const float* __restrict__ cosb,
                                                  const float* __restrict__ sinb,
                                                  short* __restrict__ Qr,
                                                  short* __restrict__ Kr,
                                                  short* __restrict__ VT) {
  __shared__ short sA[4][8192];   // [buf][256 rows][32 k], swizzled granules
  __shared__ short sB[4][8192];
  const int tid = threadIdx.x;
  const int wv = tid >> 6, lane = tid & 63;
  const int l16 = lane & 15, lhi = lane >> 4;
  const int wr = wv >> 2, wc = wv & 3;          // wave grid 2M x 4N
  const int bm = blockIdx.x * 256, bn = blockIdx.y * 256;
  const int srow0 = wv * 16 + (lane >> 2);      // staging row within 128-half
  const int sgs = lane & 3;                     // stored granule
  const int NT = K >> 5;

  auto stageA = [&](int kt, int b) {
#pragma unroll
    for (int j = 0; j < 2; ++j) {
      int row = j * 128 + srow0;
      int g = sgs ^ ((row >> 1) & 3);           // logical granule for this slot
      gld_lds16(A + (size_t)(bm + row) * K + kt + g * 8,
                &sA[b][j * 4096 + wv * 512]);   // wave-uniform base + lane*16B
    }
  };
  auto stageB = [&](int kt, int b) {
#pragma unroll
    for (int j = 0; j < 2; ++j) {
      int row = j * 128 + srow0;
      int g = sgs ^ ((row >> 1) & 3);
      gld_lds16(BT + (size_t)(bn + row) * K + kt + g * 8,
                &sB[b][j * 4096 + wv * 512]);
    }
  };

  f32x4 acc[8][4] = {};
  bf16x8 aP[8], bP[4], aQ[8], bQ[4];

#define FRAG_READ(DA, DB, BUF)                                                 \
  {                                                                            \
    const short* bufA_ = sA[(BUF)];                                            \
    const short* bufB_ = sB[(BUF)];                                            \
    _Pragma("unroll") for (int n = 0; n < 4; ++n) {                            \
      int row = wc * 64 + n * 16 + l16;                                        \
      DB[n] = *(const bf16x8*)&bufB_[row * 32 + ((lhi ^ ((row >> 1) & 3)) << 3)]; \
    }                                                                          \
    _Pragma("unroll") for (int m = 0; m < 8; ++m) {                            \
      int row = wr * 128 + m * 16 + l16;                                       \
      DA[m] = *(const bf16x8*)&bufA_[row * 32 + ((lhi ^ ((row >> 1) & 3)) << 3)]; \
    }                                                                          \
  }

#define TILE_BODY(T, CA, CB, NA, NB)                                           \
  {                                                                            \
    const int t_ = (T);                                                        \
    if (t_ + 1 < NT) FRAG_READ(NA, NB, (t_ + 1) & 3);                          \
    if (t_ + 3 < NT) {                                                         \
      stageA((t_ + 3) * 32, (t_ + 3) & 3);                                     \
      stageB((t_ + 3) * 32, (t_ + 3) & 3);                                     \
    }                                                                          \
    __builtin_amdgcn_sched_barrier(0);                                         \
    if (t_ + 3 < NT) {                                                         \
      asm volatile("s_waitcnt vmcnt(4)" ::: "memory");                         \
    } else {                                                                   \
      asm volatile("s_waitcnt vmcnt(0)" ::: "memory");                         \
    }                                                                          \
    __builtin_amdgcn_sched_barrier(0);                                         \
    __builtin_amdgcn_s_setprio(1);                                             \
    _Pragma("unroll") for (int m = 0; m < 8; ++m)                              \
        _Pragma("unroll") for (int n = 0; n < 4; ++n)                          \
            acc[m][n] = __builtin_amdgcn_mfma_f32_16x16x32_bf16(               \
                CA[m], CB[n], acc[m][n], 0, 0, 0);                             \
    __builtin_amdgcn_s_setprio(0);                                             \
    __builtin_amdgcn_sched_barrier(0);                                         \
    __builtin_amdgcn_s_barrier();                                              \
    __builtin_amdgcn_sched_barrier(0);                                         \
  }

  // prologue: stage tiles 0,1,2; publish 0 and 1; preload tile-0 frags
  stageA(0, 0); stageB(0, 0);
  stageA(32, 1); stageB(32, 1);
  stageA(64, 2); stageB(64, 2);
  asm volatile("s_waitcnt vmcnt(8)" ::: "memory");   // tile 0 landed
  __builtin_amdgcn_s_barrier();
  FRAG_READ(aP, bP, 0);
  asm volatile("s_waitcnt vmcnt(4)" ::: "memory");   // tile 1 landed
  __builtin_amdgcn_s_barrier();
  __builtin_amdgcn_sched_barrier(0);

  for (int t = 0; t < NT; t += 2) {      // NT even (K % 64 == 0)
    TILE_BODY(t, aP, bP, aQ, bQ);
    TILE_BODY(t + 1, aQ, bQ, aP, bP);
  }
#undef FRAG_READ
#undef TILE_BODY

  if constexpr (MODE == 1) {
#pragma unroll
    for (int m = 0; m < 8; ++m) {
#pragma unroll
      for (int n = 0; n < 4; ++n) {
        int col = bn + wc * 64 + n * 16 + l16;
#pragma unroll
        for (int r = 0; r < 4; ++r) {
          int row = bm + wr * 128 + m * 16 + lhi * 4 + r;
          C[(size_t)row * N + col] = acc[m][n][r];
        }
      }
    }
  } else {
    // MODE 2: fused QKV epilogue. part: 0=q, 1=k, 2=v (block-uniform).
    const int part = bn >> 11;
    const float kC = 0.08838834764831845f * 1.44269504088896340f;
    if (part < 2) {
      const float qs = (part == 0) ? kC : 1.0f;
      short* dst = (part == 0) ? Qr : Kr;
#pragma unroll
      for (int m = 0; m < 8; ++m) {
#pragma unroll
        for (int n = 0; n < 4; ++n) {
          int colm = (bn & 2047) + wc * 64 + n * 16 + l16;  // 0..2047
          int h = colm >> 7, d = colm & 127;
          int p2 = d >> 1;
          bool ev = (d & 1) == 0;
#pragma unroll
          for (int r = 0; r < 4; ++r) {
            int row = bm + wr * 128 + m * 16 + lhi * 4 + r;
            int b = row >> 11, t = row & 2047;
            float c = cosb[t * 64 + p2];
            float s = sinb[t * 64 + p2];
            float x = acc[m][n][r];
            float xp = __shfl_xor(x, 1);                    // partner d^1
            float y = ev ? (x * c - xp * s) : (xp * s + x * c);
            dst[((size_t)(b * 16 + h) * 2048 + t) * 128 + d] =
                (short)f2bf(y * qs);
          }
        }
      }
    } else {
#pragma unroll
      for (int m = 0; m < 8; ++m) {
#pragma unroll
        for (int n = 0; n < 4; ++n) {
          int colm = (bn & 2047) + wc * 64 + n * 16 + l16;
          int h = colm >> 7, d = colm & 127;
#pragma unroll
          for (int r = 0; r < 4; ++r) {
            int row = bm + wr * 128 + m * 16 + lhi * 4 + r;
            int b = row >> 11, t = row & 2047;
            VT[((size_t)(b * 16 + h) * 128 + d) * 2048 + t] =
                (short)f2bf(acc[m][n][r]);
          }
        }
      }
    }
  }
}

// ---------------- causal flash attention (v5: KVBLK=32, 36KB LDS) ---------
// block = (bh, pair): q-tiles qt=pair, 31-pair -> 66 KV iters (32-wide each).
// 4 waves x 16 q-rows. LDS: sK 2x8KB + sVT 2x8KB + sP 4KB = 36KB ->
// 4 blocks/CU = 4 waves/SIMD (2x TLP vs KVBLK=64). Same dbuf prefetch,
// ones-MFMA row-sum, defer-max THR=8, T5 setprio. Swizzles: sK granule ^
// (row&7); sVT/sP granule ^ ((row>>1)&3) (2-way residual = free).
__global__ __launch_bounds__(256) void k_attn(const short* __restrict__ Qr,
                                              const short* __restrict__ Kr,
                                              const short* __restrict__ VT,
                                              short* __restrict__ Y) {
  __shared__ short sK[2][32 * 128];    // 2 x 8KB
  __shared__ short sVT[2][128 * 32];   // 2 x 8KB
  __shared__ short sP[4][16 * 32];     // 4KB
  const int tid = threadIdx.x, wv = tid >> 6, lane = tid & 63;
  const int l16 = lane & 15, lhi = lane >> 4;
  const int bid = blockIdx.x;
  const int pair = bid & 15, bh = bid >> 4;
  const size_t base = (size_t)bh * 2048 * 128;
  const int b = bh >> 4, h = bh & 15;

  const short ob = (short)0x3F80;                   // bf16 1.0
  const bf16x8 ones = {ob, ob, ob, ob, ob, ob, ob, ob};

  auto stage = [&](int kv0, int buf) {
#pragma unroll
    for (int rr = 0; rr < 2; ++rr) {
      int ch = rr * 4 + wv;
      {                                 // sK: 32 rows x 256B; chunk = 4 rows
        int row = ch * 4 + lhi;
        int g = l16 ^ (row & 7);        // stored slot l16 holds granule l16^(row&7)
        gld_lds16(Kr + base + (size_t)(kv0 + row) * 128 + g * 8,
                  &sK[buf][ch * 512]);
      }
      {                                 // sVT: 128 rows x 64B; chunk = 16 rows
        int drow = ch * 16 + (lane >> 2);
        int g = (lane & 3) ^ ((drow >> 1) & 3);
        gld_lds16(VT + base + (size_t)drow * 2048 + kv0 + g * 8,
                  &sVT[buf][ch * 512]);
      }
    }
  };

  for (int half = 0; half < 2; ++half) {
    const int qt = half ? 31 - pair : pair;
    const int q0 = qt * 64;
    const int nt = 2 * qt + 2;          // 32-wide KV tiles

    bf16x8 qf[4];
    const int qrow = q0 + wv * 16 + l16;
#pragma unroll
    for (int ks = 0; ks < 4; ++ks)
      qf[ks] = *reinterpret_cast<const bf16x8*>(Qr + base + (size_t)qrow * 128 +
                                                ks * 32 + lhi * 8);

    f32x4 acc_o[8] = {};
    f32x4 acc_l = {};
    float m_run[4];
#pragma unroll
    for (int r = 0; r < 4; ++r) m_run[r] = -1e30f;

    stage(0, 0);
    __syncthreads();

    for (int it = 0; it < nt; ++it) {
      const int cur = it & 1;
      if (it + 1 < nt) stage((it + 1) * 32, cur ^ 1);   // prefetch next tile

      // S = Q K^T (exp2 domain; kC folded into Q). 2 col-frags of 16.
      f32x4 sacc[2] = {};
      __builtin_amdgcn_s_setprio(1);
#pragma unroll
      for (int cf = 0; cf < 2; ++cf) {
        int krow = cf * 16 + l16;
#pragma unroll
        for (int ks = 0; ks < 4; ++ks) {
          int e = krow * 128 + (((ks * 4 + lhi) ^ (krow & 7)) << 3);
          bf16x8 kf = *reinterpret_cast<const bf16x8*>(&sK[cur][e]);
          sacc[cf] = __builtin_amdgcn_mfma_f32_16x16x32_bf16(qf[ks], kf,
                                                             sacc[cf], 0, 0, 0);
        }
      }
      __builtin_amdgcn_s_setprio(0);

      if (it >= nt - 2) {                // causal mask: last two 32-wide tiles
        const int rel = it * 32 - q0;    // 0 or 32
#pragma unroll
        for (int cf = 0; cf < 2; ++cf) {
          int col = rel + cf * 16 + l16;
#pragma unroll
          for (int r = 0; r < 4; ++r)
            if (col > wv * 16 + lhi * 4 + r) sacc[cf][r] = -3e38f;
        }
      }

      // defer-max: slow path only when a row max grows past THR=8 (exp2-units)
      bool exceed = false;
#pragma unroll
      for (int cf = 0; cf < 2; ++cf)
#pragma unroll
        for (int r = 0; r < 4; ++r)
          exceed |= (sacc[cf][r] > m_run[r] + 8.f);

      if (__any(exceed)) {
        float resc[4];
#pragma unroll
        for (int r = 0; r < 4; ++r) {
          float mx = fmaxf(sacc[0][r], sacc[1][r]);
          mx = fmaxf(mx, __shfl_xor(mx, 1));
          mx = fmaxf(mx, __shfl_xor(mx, 2));
          mx = fmaxf(mx, __shfl_xor(mx, 4));
          mx = fmaxf(mx, __shfl_xor(mx, 8));
          float mnew = fmaxf(m_run[r], mx);
          resc[r] = exp2f(m_run[r] - mnew);
          m_run[r] = mnew;
        }
#pragma unroll
        for (int df = 0; df < 8; ++df)
#pragma unroll
          for (int r = 0; r < 4; ++r) acc_o[df][r] *= resc[r];
#pragma unroll
        for (int r = 0; r < 4; ++r) acc_l[r] *= resc[r];
      }

      // P = exp2(S - m), bf16, into per-wave swizzled LDS (A-frag reshape)
#pragma unroll
      for (int cf = 0; cf < 2; ++cf)
#pragma unroll
        for (int r = 0; r < 4; ++r) {
          float p = exp2f(sacc[cf][r] - m_run[r]);
          int prow = lhi * 4 + r;
          int c = cf * 16 + l16;
          int s = prow * 32 + ((((c >> 3) ^ ((prow >> 1) & 3)) << 3)) + (c & 7);
          sP[wv][s] = (short)f2bf(p);
        }

      // O += P V ; l += P * ones  (K=32 contraction, single step)
      __builtin_amdgcn_s_setprio(1);
      {
        int e = l16 * 32 + ((lhi ^ ((l16 >> 1) & 3)) << 3);
        bf16x8 pa = *reinterpret_cast<const bf16x8*>(&sP[wv][e]);
        acc_l = __builtin_amdgcn_mfma_f32_16x16x32_bf16(pa, ones, acc_l, 0, 0, 0);
#pragma unroll
        for (int df = 0; df < 8; ++df) {
          int vrow = df * 16 + l16;
          int ev = vrow * 32 + ((lhi ^ ((vrow >> 1) & 3)) << 3);
          bf16x8 vb = *reinterpret_cast<const bf16x8*>(&sVT[cur][ev]);
          acc_o[df] = __builtin_amdgcn_mfma_f32_16x16x32_bf16(pa, vb,
                                                              acc_o[df], 0, 0, 0);
        }
      }
      __builtin_amdgcn_s_setprio(0);
      __syncthreads();   // drains prefetch vmcnt + protects LDS buffers
    }

    float inv[4];
#pragma unroll
    for (int r = 0; r < 4; ++r) inv[r] = 1.f / acc_l[r];
#pragma unroll
    for (int df = 0; df < 8; ++df) {
      int col = h * 128 + df * 16 + l16;
#pragma unroll
      for (int r = 0; r < 4; ++r) {
        int row = q0 + wv * 16 + lhi * 4 + r;
        Y[((size_t)b * 2048 + row) * 2048 + col] =
            (short)f2bf(acc_o[df][r] * inv[r]);
      }
    }
  }
}

// ---------------- launch ----------------
extern "C" void kernel_launch(void* const* d_in, const int* in_sizes, int n_in,
                              void* d_out, int out_size, void* d_ws, size_t ws_size,
                              hipStream_t stream) {
  const float* x        = (const float*)d_in[0];
  const float* w_attn   = (const float*)d_in[1];
  const float* w_proj   = (const float*)d_in[2];
  const float* rope_cos = (const float*)d_in[3];
  const float* rope_sin = (const float*)d_in[4];

  char* ws = (char*)d_ws;                     // 256 MiB total layout
  short* xbf    = (short*)(ws);               // 33.5 MB  [8192][2048]
  short* wattnT = (short*)(ws + 33554432ull); // 25.2 MB  [6144][2048]
  short* wprojT = (short*)(ws + 58720256ull); //  8.4 MB  [2048][2048]
  short* Y      = (short*)(ws + 67108864ull); // 33.5 MB  [8192][2048]
  short* Qr     = (short*)(ws + 167772160ull);// 33.5 MB  [B,H,T,128]
  short* Kr     = (short*)(ws + 201326592ull);// 33.5 MB  [B,H,T,128]
  short* VT     = (short*)(ws + 234881024ull);// 33.5 MB  [B,H,128,T]

  k_conv<<<16384, 256, 0, stream>>>(x, xbf, 4194304);
  k_transpose<<<3072, 256, 0, stream>>>(w_attn, wattnT, 2048, 6144);
  k_transpose<<<1024, 256, 0, stream>>>(w_proj, wprojT, 2048, 2048);
  k_gemm8<2, short><<<dim3(32, 24), 512, 0, stream>>>(
      xbf, wattnT, (short*)nullptr, 8192, 6144, 2048,
      rope_cos, rope_sin, Qr, Kr, VT);
  k_attn<<<1024, 256, 0, stream>>>(Qr, Kr, VT, Y);
  k_gemm8<1, float><<<dim3(32, 8), 512, 0, stream>>>(
      Y, wprojT, (float*)d_out, 8192, 2048, 2048,
      nullptr, nullptr, nullptr, nullptr, nullptr);
}

// Round 13
// 470.742 us; speedup vs baseline: 1.0430x; 1.0430x over previous
//
#include <hip/hip_runtime.h>
#include <cstdint>
#include <cstddef>

#define DEVI __device__ __forceinline__

typedef __attribute__((ext_vector_type(8))) short bf16x8;
typedef __attribute__((ext_vector_type(4))) float f32x4;

DEVI unsigned short f2bf(float f) {
  unsigned int u = __float_as_uint(f);
  u += 0x7fffu + ((u >> 16) & 1u);   // RNE
  return (unsigned short)(u >> 16);
}
DEVI float bf2f(unsigned int us) { return __uint_as_float(us << 16); }

DEVI void gld_lds16(const void* g, void* l) {
  __builtin_amdgcn_global_load_lds(
      (const __attribute__((address_space(1))) void*)g,
      (__attribute__((address_space(3))) void*)l, 16, 0, 0);
}

// ---------------- fused prep: x->bf16 conv + both weight transposes -------
// blocks [0,16384): conv x (4096x... 4194304 float4 groups)
// blocks [16384,19456): transpose w_attn 2048x6144 -> bf16 [6144][2048]
// blocks [19456,20480): transpose w_proj 2048x2048 -> bf16 [2048][2048]
// Branch is block-uniform; __syncthreads only in transpose branches.
__global__ __launch_bounds__(256) void k_prep(const float* __restrict__ x,
                                              short* __restrict__ xbf,
                                              const float* __restrict__ w_attn,
                                              short* __restrict__ wattnT,
                                              const float* __restrict__ w_proj,
                                              short* __restrict__ wprojT) {
  const int bid = blockIdx.x, tid = threadIdx.x;
  if (bid < 16384) {
    int i = bid * 256 + tid;
    float4 v = reinterpret_cast<const float4*>(x)[i];
    uint2 o;
    o.x = (unsigned)f2bf(v.x) | ((unsigned)f2bf(v.y) << 16);
    o.y = (unsigned)f2bf(v.z) | ((unsigned)f2bf(v.w) << 16);
    reinterpret_cast<uint2*>(xbf)[i] = o;
    return;
  }
  __shared__ short tile[64][66];
  const float* in;
  short* out;
  int R, Cc, tb, rb;
  if (bid < 19456) {
    in = w_attn; out = wattnT; R = 2048; Cc = 6144;
    int t = bid - 16384; tb = t % 96; rb = t / 96;
  } else {
    in = w_proj; out = wprojT; R = 2048; Cc = 2048;
    int t = bid - 19456; tb = t % 32; rb = t / 32;
  }
#pragma unroll
  for (int rep = 0; rep < 16; ++rep) {
    int idx = rep * 256 + tid;
    int r = idx >> 6, c = idx & 63;
    tile[r][c] = (short)f2bf(in[(size_t)(rb * 64 + r) * Cc + tb * 64 + c]);
  }
  __syncthreads();
#pragma unroll
  for (int rep = 0; rep < 16; ++rep) {
    int idx = rep * 256 + tid;
    int r = idx >> 6, c = idx & 63;
    out[(size_t)(tb * 64 + r) * R + rb * 64 + c] = tile[c][r];
  }
}

// ---------------- bf16 GEMM, B^T input (round-4 pipeline, proven) ---------
// BM=BN=256, BK=32, 512 thr (8 waves 2Mx4N), 4 LDS buffers (128KB).
// Staging 3 K-tiles ahead; one counted vmcnt(4) + one s_barrier per tile.
// Register frag double-buffer. 2D grid.
// MODE 1: plain fp32 C.  MODE 2: fused QKV epilogue (RoPE'd Q,K + V^T).
template <int MODE, typename OutT>
__global__ __launch_bounds__(512, 2) void k_gemm8(const short* __restrict__ A,
                                                  const short* __restrict__ BT,
                                                  OutT* __restrict__ C,
                                                  int M, int N, int K,
                                                  const float* __restrict__ cosb,
                                                  const float* __restrict__ sinb,
                                                  short* __restrict__ Qr,
                                                  short* __restrict__ Kr,
                                                  short* __restrict__ VT) {
  __shared__ short sA[4][8192];   // [buf][256 rows][32 k], swizzled granules
  __shared__ short sB[4][8192];
  const int tid = threadIdx.x;
  const int wv = tid >> 6, lane = tid & 63;
  const int l16 = lane & 15, lhi = lane >> 4;
  const int wr = wv >> 2, wc = wv & 3;          // wave grid 2M x 4N
  const int bm = blockIdx.x * 256, bn = blockIdx.y * 256;
  const int srow0 = wv * 16 + (lane >> 2);      // staging row within 128-half
  const int sgs = lane & 3;                     // stored granule
  const int NT = K >> 5;

  auto stageA = [&](int kt, int b) {
#pragma unroll
    for (int j = 0; j < 2; ++j) {
      int row = j * 128 + srow0;
      int g = sgs ^ ((row >> 1) & 3);           // logical granule for this slot
      gld_lds16(A + (size_t)(bm + row) * K + kt + g * 8,
                &sA[b][j * 4096 + wv * 512]);   // wave-uniform base + lane*16B
    }
  };
  auto stageB = [&](int kt, int b) {
#pragma unroll
    for (int j = 0; j < 2; ++j) {
      int row = j * 128 + srow0;
      int g = sgs ^ ((row >> 1) & 3);
      gld_lds16(BT + (size_t)(bn + row) * K + kt + g * 8,
                &sB[b][j * 4096 + wv * 512]);
    }
  };

  f32x4 acc[8][4] = {};
  bf16x8 aP[8], bP[4], aQ[8], bQ[4];

#define FRAG_READ(DA, DB, BUF)                                                 \
  {                                                                            \
    const short* bufA_ = sA[(BUF)];                                            \
    const short* bufB_ = sB[(BUF)];                                            \
    _Pragma("unroll") for (int n = 0; n < 4; ++n) {                            \
      int row = wc * 64 + n * 16 + l16;                                        \
      DB[n] = *(const bf16x8*)&bufB_[row * 32 + ((lhi ^ ((row >> 1) & 3)) << 3)]; \
    }                                                                          \
    _Pragma("unroll") for (int m = 0; m < 8; ++m) {                            \
      int row = wr * 128 + m * 16 + l16;                                       \
      DA[m] = *(const bf16x8*)&bufA_[row * 32 + ((lhi ^ ((row >> 1) & 3)) << 3)]; \
    }                                                                          \
  }

#define TILE_BODY(T, CA, CB, NA, NB)                                           \
  {                                                                            \
    const int t_ = (T);                                                        \
    if (t_ + 1 < NT) FRAG_READ(NA, NB, (t_ + 1) & 3);                          \
    if (t_ + 3 < NT) {                                                         \
      stageA((t_ + 3) * 32, (t_ + 3) & 3);                                     \
      stageB((t_ + 3) * 32, (t_ + 3) & 3);                                     \
    }                                                                          \
    __builtin_amdgcn_sched_barrier(0);                                         \
    if (t_ + 3 < NT) {                                                         \
      asm volatile("s_waitcnt vmcnt(4)" ::: "memory");                         \
    } else {                                                                   \
      asm volatile("s_waitcnt vmcnt(0)" ::: "memory");                         \
    }                                                                          \
    __builtin_amdgcn_sched_barrier(0);                                         \
    __builtin_amdgcn_s_setprio(1);                                             \
    _Pragma("unroll") for (int m = 0; m < 8; ++m)                              \
        _Pragma("unroll") for (int n = 0; n < 4; ++n)                          \
            acc[m][n] = __builtin_amdgcn_mfma_f32_16x16x32_bf16(               \
                CA[m], CB[n], acc[m][n], 0, 0, 0);                             \
    __builtin_amdgcn_s_setprio(0);                                             \
    __builtin_amdgcn_sched_barrier(0);                                         \
    __builtin_amdgcn_s_barrier();                                              \
    __builtin_amdgcn_sched_barrier(0);                                         \
  }

  // prologue: stage tiles 0,1,2; publish 0 and 1; preload tile-0 frags
  stageA(0, 0); stageB(0, 0);
  stageA(32, 1); stageB(32, 1);
  stageA(64, 2); stageB(64, 2);
  asm volatile("s_waitcnt vmcnt(8)" ::: "memory");   // tile 0 landed
  __builtin_amdgcn_s_barrier();
  FRAG_READ(aP, bP, 0);
  asm volatile("s_waitcnt vmcnt(4)" ::: "memory");   // tile 1 landed
  __builtin_amdgcn_s_barrier();
  __builtin_amdgcn_sched_barrier(0);

  for (int t = 0; t < NT; t += 2) {      // NT even (K % 64 == 0)
    TILE_BODY(t, aP, bP, aQ, bQ);
    TILE_BODY(t + 1, aQ, bQ, aP, bP);
  }
#undef FRAG_READ
#undef TILE_BODY

  if constexpr (MODE == 1) {
#pragma unroll
    for (int m = 0; m < 8; ++m) {
#pragma unroll
      for (int n = 0; n < 4; ++n) {
        int col = bn + wc * 64 + n * 16 + l16;
#pragma unroll
        for (int r = 0; r < 4; ++r) {
          int row = bm + wr * 128 + m * 16 + lhi * 4 + r;
          C[(size_t)row * N + col] = acc[m][n][r];
        }
      }
    }
  } else {
    // MODE 2: fused QKV epilogue. part: 0=q, 1=k, 2=v (block-uniform).
    const int part = bn >> 11;
    const float kC = 0.08838834764831845f * 1.44269504088896340f;
    if (part < 2) {
      const float qs = (part == 0) ? kC : 1.0f;
      short* dst = (part == 0) ? Qr : Kr;
#pragma unroll
      for (int m = 0; m < 8; ++m) {
#pragma unroll
        for (int n = 0; n < 4; ++n) {
          int colm = (bn & 2047) + wc * 64 + n * 16 + l16;  // 0..2047
          int h = colm >> 7, d = colm & 127;
          int p2 = d >> 1;
          bool ev = (d & 1) == 0;
#pragma unroll
          for (int r = 0; r < 4; ++r) {
            int row = bm + wr * 128 + m * 16 + lhi * 4 + r;
            int b = row >> 11, t = row & 2047;
            float c = cosb[t * 64 + p2];
            float s = sinb[t * 64 + p2];
            float x = acc[m][n][r];
            float xp = __shfl_xor(x, 1);                    // partner d^1
            float y = ev ? (x * c - xp * s) : (xp * s + x * c);
            dst[((size_t)(b * 16 + h) * 2048 + t) * 128 + d] =
                (short)f2bf(y * qs);
          }
        }
      }
    } else {
#pragma unroll
      for (int m = 0; m < 8; ++m) {
#pragma unroll
        for (int n = 0; n < 4; ++n) {
          int colm = (bn & 2047) + wc * 64 + n * 16 + l16;
          int h = colm >> 7, d = colm & 127;
#pragma unroll
          for (int r = 0; r < 4; ++r) {
            int row = bm + wr * 128 + m * 16 + lhi * 4 + r;
            int b = row >> 11, t = row & 2047;
            VT[((size_t)(b * 16 + h) * 128 + d) * 2048 + t] =
                (short)f2bf(acc[m][n][r]);
          }
        }
      }
    }
  }
}

// ---------------- causal flash attention (round-2 v2, proven 150us) -------
// block = (bh, pair): q-tiles qt=pair and qt=31-pair -> 33 KV iters/block.
// 4 waves x 16 q-rows, KVBLK=64, double-buffered K/V via global_load_lds.
// Row-sum of P via MFMA with all-ones B; defer-max (THR=8, exp2 domain).
__global__ __launch_bounds__(256) void k_attn(const short* __restrict__ Qr,
                                              const short* __restrict__ Kr,
                                              const short* __restrict__ VT,
                                              short* __restrict__ Y) {
  __shared__ short sK[2][64 * 128];
  __shared__ short sVT[2][128 * 64];
  __shared__ short sP[4][16 * 64];
  const int tid = threadIdx.x, wv = tid >> 6, lane = tid & 63;
  const int l8r = lane >> 3, l8c = lane & 7, l16 = lane & 15, lhi = lane >> 4;
  const int bid = blockIdx.x;
  const int pair = bid & 15, bh = bid >> 4;
  const size_t base = (size_t)bh * 2048 * 128;
  const int b = bh >> 4, h = bh & 15;

  const short ob = (short)0x3F80;                   // bf16 1.0
  const bf16x8 ones = {ob, ob, ob, ob, ob, ob, ob, ob};

  auto stage = [&](int kv0, int buf) {
#pragma unroll
    for (int rr = 0; rr < 4; ++rr) {
      int ch = rr * 4 + wv;
      {                                    // sK: row stride 256B, chunk = 4 rows
        int row = ch * 4 + lhi;
        int wch = l16 ^ (row & 7);         // inverse-swizzled source chunk
        gld_lds16(Kr + base + (size_t)(kv0 + row) * 128 + wch * 8,
                  &sK[buf][ch * 512]);
      }
      {                                    // sVT: row stride 128B, chunk = 8 rows
        int drow = ch * 8 + l8r;
        int wch = l8c ^ (drow & 7);
        gld_lds16(VT + base + (size_t)drow * 2048 + kv0 + wch * 8,
                  &sVT[buf][ch * 512]);
      }
    }
  };

  for (int half = 0; half < 2; ++half) {
    const int qt = half ? 31 - pair : pair;
    const int q0 = qt * 64;
    const int nt = qt + 1;

    bf16x8 qf[4];
    const int qrow = q0 + wv * 16 + l16;
#pragma unroll
    for (int ks = 0; ks < 4; ++ks)
      qf[ks] = *reinterpret_cast<const bf16x8*>(Qr + base + (size_t)qrow * 128 +
                                                ks * 32 + lhi * 8);

    f32x4 acc_o[8] = {};
    f32x4 acc_l = {};
    float m_run[4];
#pragma unroll
    for (int r = 0; r < 4; ++r) m_run[r] = -1e30f;

    stage(0, 0);
    __syncthreads();

    for (int it = 0; it < nt; ++it) {
      const int cur = it & 1;
      if (it + 1 < nt) stage((it + 1) * 64, cur ^ 1);   // prefetch next tile

      // S = Q K^T  (scores already in exp2 domain: kC folded into Q)
      f32x4 sacc[4] = {};
#pragma unroll
      for (int cf = 0; cf < 4; ++cf) {
        int krow = cf * 16 + l16;
#pragma unroll
        for (int ks = 0; ks < 4; ++ks) {
          int e = krow * 128 + ks * 32 + lhi * 8;
          bf16x8 kf = *reinterpret_cast<const bf16x8*>(
              &sK[cur][e ^ ((krow & 7) << 3)]);
          sacc[cf] = __builtin_amdgcn_mfma_f32_16x16x32_bf16(qf[ks], kf,
                                                             sacc[cf], 0, 0, 0);
        }
      }

      if (it == nt - 1) {                  // causal mask on diagonal tile
#pragma unroll
        for (int cf = 0; cf < 4; ++cf) {
          int col = cf * 16 + l16;
#pragma unroll
          for (int r = 0; r < 4; ++r)
            if (col > wv * 16 + lhi * 4 + r) sacc[cf][r] = -3e38f;
        }
      }

      // defer-max: slow path only when a row max grows past THR=8 (exp2-units)
      bool exceed = false;
#pragma unroll
      for (int cf = 0; cf < 4; ++cf)
#pragma unroll
        for (int r = 0; r < 4; ++r)
          exceed |= (sacc[cf][r] > m_run[r] + 8.f);

      if (__any(exceed)) {
        float resc[4];
#pragma unroll
        for (int r = 0; r < 4; ++r) {
          float mx = fmaxf(fmaxf(sacc[0][r], sacc[1][r]),
                           fmaxf(sacc[2][r], sacc[3][r]));
          mx = fmaxf(mx, __shfl_xor(mx, 1));
          mx = fmaxf(mx, __shfl_xor(mx, 2));
          mx = fmaxf(mx, __shfl_xor(mx, 4));
          mx = fmaxf(mx, __shfl_xor(mx, 8));
          float mnew = fmaxf(m_run[r], mx);
          resc[r] = exp2f(m_run[r] - mnew);
          m_run[r] = mnew;
        }
#pragma unroll
        for (int df = 0; df < 8; ++df)
#pragma unroll
          for (int r = 0; r < 4; ++r) acc_o[df][r] *= resc[r];
#pragma unroll
        for (int r = 0; r < 4; ++r) acc_l[r] *= resc[r];
      }

      // P = exp2(S - m), bf16, into per-wave swizzled LDS (A-frag reshape)
#pragma unroll
      for (int cf = 0; cf < 4; ++cf)
#pragma unroll
        for (int r = 0; r < 4; ++r) {
          float p = exp2f(sacc[cf][r] - m_run[r]);
          int prow = lhi * 4 + r;
          int e = prow * 64 + cf * 16 + l16;
          sP[wv][e ^ ((prow & 7) << 3)] = (short)f2bf(p);
        }

      // O += P V ; l += P * ones  (row-sum via MFMA, no shuffle reduce)
#pragma unroll
      for (int kk = 0; kk < 2; ++kk) {
        int e = l16 * 64 + kk * 32 + lhi * 8;
        bf16x8 pa = *reinterpret_cast<const bf16x8*>(
            &sP[wv][e ^ ((l16 & 7) << 3)]);
        acc_l = __builtin_amdgcn_mfma_f32_16x16x32_bf16(pa, ones, acc_l, 0, 0, 0);
#pragma unroll
        for (int df = 0; df < 8; ++df) {
          int vrow = df * 16 + l16;
          int ev = vrow * 64 + kk * 32 + lhi * 8;
          bf16x8 vb = *reinterpret_cast<const bf16x8*>(
              &sVT[cur][ev ^ ((vrow & 7) << 3)]);
          acc_o[df] = __builtin_amdgcn_mfma_f32_16x16x32_bf16(pa, vb,
                                                              acc_o[df], 0, 0, 0);
        }
      }
      __syncthreads();   // drains prefetch vmcnt + protects LDS buffers
    }

    float inv[4];
#pragma unroll
    for (int r = 0; r < 4; ++r) inv[r] = 1.f / acc_l[r];
#pragma unroll
    for (int df = 0; df < 8; ++df) {
      int col = h * 128 + df * 16 + l16;
#pragma unroll
      for (int r = 0; r < 4; ++r) {
        int row = q0 + wv * 16 + lhi * 4 + r;
        Y[((size_t)b * 2048 + row) * 2048 + col] =
            (short)f2bf(acc_o[df][r] * inv[r]);
      }
    }
  }
}

// ---------------- launch ----------------
extern "C" void kernel_launch(void* const* d_in, const int* in_sizes, int n_in,
                              void* d_out, int out_size, void* d_ws, size_t ws_size,
                              hipStream_t stream) {
  const float* x        = (const float*)d_in[0];
  const float* w_attn   = (const float*)d_in[1];
  const float* w_proj   = (const float*)d_in[2];
  const float* rope_cos = (const float*)d_in[3];
  const float* rope_sin = (const float*)d_in[4];

  char* ws = (char*)d_ws;                     // 256 MiB total layout
  short* xbf    = (short*)(ws);               // 33.5 MB  [8192][2048]
  short* wattnT = (short*)(ws + 33554432ull); // 25.2 MB  [6144][2048]
  short* wprojT = (short*)(ws + 58720256ull); //  8.4 MB  [2048][2048]
  short* Y      = (short*)(ws + 67108864ull); // 33.5 MB  [8192][2048]
  short* Qr     = (short*)(ws + 167772160ull);// 33.5 MB  [B,H,T,128]
  short* Kr     = (short*)(ws + 201326592ull);// 33.5 MB  [B,H,T,128]
  short* VT     = (short*)(ws + 234881024ull);// 33.5 MB  [B,H,128,T]

  k_prep<<<20480, 256, 0, stream>>>(x, xbf, w_attn, wattnT, w_proj, wprojT);
  k_gemm8<2, short><<<dim3(32, 24), 512, 0, stream>>>(
      xbf, wattnT, (short*)nullptr, 8192, 6144, 2048,
      rope_cos, rope_sin, Qr, Kr, VT);
  k_attn<<<1024, 256, 0, stream>>>(Qr, Kr, VT, Y);
  k_gemm8<1, float><<<dim3(32, 8), 512, 0, stream>>>(
      Y, wprojT, (float*)d_out, 8192, 2048, 2048,
      nullptr, nullptr, nullptr, nullptr, nullptr);
}

// Round 14
// 464.296 us; speedup vs baseline: 1.0575x; 1.0139x over previous
//
#include <hip/hip_runtime.h>
#include <cstdint>
#include <cstddef>

#define DEVI __device__ __forceinline__

typedef __attribute__((ext_vector_type(8))) short bf16x8;
typedef __attribute__((ext_vector_type(4))) float f32x4;

DEVI unsigned short f2bf(float f) {
  unsigned int u = __float_as_uint(f);
  u += 0x7fffu + ((u >> 16) & 1u);   // RNE
  return (unsigned short)(u >> 16);
}
DEVI float bf2f(unsigned int us) { return __uint_as_float(us << 16); }

DEVI void gld_lds16(const void* g, void* l) {
  __builtin_amdgcn_global_load_lds(
      (const __attribute__((address_space(1))) void*)g,
      (__attribute__((address_space(3))) void*)l, 16, 0, 0);
}

// ---------------- fused prep: x->bf16 conv + both weight transposes -------
__global__ __launch_bounds__(256) void k_prep(const float* __restrict__ x,
                                              short* __restrict__ xbf,
                                              const float* __restrict__ w_attn,
                                              short* __restrict__ wattnT,
                                              const float* __restrict__ w_proj,
                                              short* __restrict__ wprojT) {
  const int bid = blockIdx.x, tid = threadIdx.x;
  if (bid < 16384) {
    int i = bid * 256 + tid;
    float4 v = reinterpret_cast<const float4*>(x)[i];
    uint2 o;
    o.x = (unsigned)f2bf(v.x) | ((unsigned)f2bf(v.y) << 16);
    o.y = (unsigned)f2bf(v.z) | ((unsigned)f2bf(v.w) << 16);
    reinterpret_cast<uint2*>(xbf)[i] = o;
    return;
  }
  __shared__ short tile[64][66];
  const float* in;
  short* out;
  int R, Cc, tb, rb;
  if (bid < 19456) {
    in = w_attn; out = wattnT; R = 2048; Cc = 6144;
    int t = bid - 16384; tb = t % 96; rb = t / 96;
  } else {
    in = w_proj; out = wprojT; R = 2048; Cc = 2048;
    int t = bid - 19456; tb = t % 32; rb = t / 32;
  }
#pragma unroll
  for (int rep = 0; rep < 16; ++rep) {
    int idx = rep * 256 + tid;
    int r = idx >> 6, c = idx & 63;
    tile[r][c] = (short)f2bf(in[(size_t)(rb * 64 + r) * Cc + tb * 64 + c]);
  }
  __syncthreads();
#pragma unroll
  for (int rep = 0; rep < 16; ++rep) {
    int idx = rep * 256 + tid;
    int r = idx >> 6, c = idx & 63;
    out[(size_t)(tb * 64 + r) * R + rb * 64 + c] = tile[c][r];
  }
}

// ---------------- bf16 GEMM: 4-phase/K-tile, unpinned (m201-faithful) -----
// BM=BN=256, BK=64, 512 thr (8 waves 2Mx4N), 2 LDS bufs (128KB).
// Per phase: {ds-read one reg subtile | stage one 16KB half of tile t+1} ->
// barrier -> 16-MFMA quadrant (setprio) -> barrier. NO sched_barrier pins,
// NO explicit lgkmcnt (compiler emits counted waits for visible ds_reads).
// Counted vmcnt(4) gates ONLY at P1 and P3 (race-free by in-order
// retirement: P3(t-1) guarantees t's A0,B0; P1(t) guarantees t's B1,A1).
// Quadrant Qd pipelined one phase (computed at next tile's P0).
// MODE 1: plain fp32 C.  MODE 2: fused QKV epilogue (RoPE'd Q,K + V^T).
template <int MODE, typename OutT>
__global__ __launch_bounds__(512, 2) void k_gemm10(const short* __restrict__ A,
                                                   const short* __restrict__ BT,
                                                   OutT* __restrict__ C,
                                                   int M, int N, int K,
                                                   const float* __restrict__ cosb,
                                                   const float* __restrict__ sinb,
                                                   short* __restrict__ Qr,
                                                   short* __restrict__ Kr,
                                                   short* __restrict__ VT) {
  __shared__ short sA[2][256 * 64];
  __shared__ short sB[2][256 * 64];
  const int tid = threadIdx.x;
  const int wv = tid >> 6, lane = tid & 63;
  const int l16 = lane & 15, lhi = lane >> 4;
  const int wr = wv >> 2, wc = wv & 3;          // wave grid 2M x 4N
  const int bm = blockIdx.x * 256, bn = blockIdx.y * 256;
  const int NT = K >> 6;                        // BK=64 tiles
  const int lr8 = lane >> 3, lg8 = lane & 7;

  // A half0 = rows [0,64)u[128,192) (af m0-3), half1 = +64 (af m4-7).
  // B half0 = {0,64,128,192}+[0,32) (bf n0-1), half1 = +32 (bf n2-3).
  // Linear dest per 8-row wave chunk; source granule pre-swizzled
  // g = (lane&7)^(row&7) with row&7 == lane>>3.
  auto stageA = [&](int half, int kt, int b) {
#pragma unroll
    for (int j = 0; j < 2; ++j) {
      int row0 = j * 128 + wv * 8 + half * 64;
      int row = row0 + lr8;
      int g = lg8 ^ lr8;
      gld_lds16(A + (size_t)(bm + row) * K + kt + g * 8, &sA[b][row0 * 64]);
    }
  };
  auto stageB = [&](int half, int kt, int b) {
#pragma unroll
    for (int j = 0; j < 2; ++j) {
      int ri0 = j * 64 + wv * 8;
      int row0 = (ri0 >> 5) * 64 + half * 32 + (ri0 & 31);
      int row = row0 + lr8;
      int g = lg8 ^ lr8;
      gld_lds16(BT + (size_t)(bn + row) * K + kt + g * 8, &sB[b][row0 * 64]);
    }
  };

  f32x4 acc[8][4] = {};
  bf16x8 af03[4][2], af47[4][2], bf01[2][2], bf23[2][2];

#define RD_A(DST, MB, BUF)                                                     \
  _Pragma("unroll") for (int m = 0; m < 4; ++m)                                \
      _Pragma("unroll") for (int ks = 0; ks < 2; ++ks) {                       \
    int row = wr * 128 + ((MB) + m) * 16 + l16;                                \
    DST[m][ks] = *(const bf16x8*)&(BUF)[row * 64 +                             \
                                        (((ks * 4 + lhi) ^ (row & 7)) << 3)];  \
  }
#define RD_B(DST, NB, BUF)                                                     \
  _Pragma("unroll") for (int n = 0; n < 2; ++n)                                \
      _Pragma("unroll") for (int ks = 0; ks < 2; ++ks) {                       \
    int row = wc * 64 + ((NB) + n) * 16 + l16;                                 \
    DST[n][ks] = *(const bf16x8*)&(BUF)[row * 64 +                             \
                                        (((ks * 4 + lhi) ^ (row & 7)) << 3)];  \
  }
#define MMA_Q(AF, BF, MO, NO)                                                  \
  __builtin_amdgcn_s_setprio(1);                                               \
  _Pragma("unroll") for (int m = 0; m < 4; ++m)                                \
      _Pragma("unroll") for (int n = 0; n < 2; ++n)                            \
          _Pragma("unroll") for (int ks = 0; ks < 2; ++ks)                     \
              acc[(MO) + m][(NO) + n] = __builtin_amdgcn_mfma_f32_16x16x32_bf16(\
                  AF[m][ks], BF[n][ks], acc[(MO) + m][(NO) + n], 0, 0, 0);     \
  __builtin_amdgcn_s_setprio(0);

  // prologue: stage tile 0's 4 halves, drain, publish
  stageA(0, 0, 0); stageB(0, 0, 0); stageB(1, 0, 0); stageA(1, 0, 0);
  asm volatile("s_waitcnt vmcnt(0)" ::: "memory");
  __builtin_amdgcn_s_barrier();

  for (int t = 0; t < NT; ++t) {
    const int cur = t & 1, nxt = cur ^ 1;
    const int kt1 = (t + 1) * 64;
    const bool pf = (t + 1 < NT);
    const short* bufA = sA[cur];
    const short* bufB = sB[cur];
    // ---- P0: read af m0-3 | stage A-half0(t+1) | MFMA Qd of t-1 ----
    RD_A(af03, 0, bufA);
    if (pf) stageA(0, kt1, nxt);
    __builtin_amdgcn_s_barrier();
    if (t) { MMA_Q(af47, bf23, 4, 2); }
    __builtin_amdgcn_s_barrier();
    // ---- P1: read bf n0-1 | stage B-half0 | gate | MFMA Qa ----
    RD_B(bf01, 0, bufB);
    if (pf) {
      stageB(0, kt1, nxt);
      asm volatile("s_waitcnt vmcnt(4)" ::: "memory");   // t's B1,A1 landed
    } else {
      asm volatile("s_waitcnt vmcnt(0)" ::: "memory");
    }
    __builtin_amdgcn_s_barrier();
    MMA_Q(af03, bf01, 0, 0);
    __builtin_amdgcn_s_barrier();
    // ---- P2: read bf n2-3 | stage B-half1 | MFMA Qb ----
    RD_B(bf23, 2, bufB);
    if (pf) stageB(1, kt1, nxt);
    __builtin_amdgcn_s_barrier();
    MMA_Q(af03, bf23, 0, 2);
    __builtin_amdgcn_s_barrier();
    // ---- P3: read af m4-7 | stage A-half1 | gate | MFMA Qc ----
    RD_A(af47, 4, bufA);
    if (pf) {
      stageA(1, kt1, nxt);
      asm volatile("s_waitcnt vmcnt(4)" ::: "memory");   // t+1's A0,B0 landed
    } else {
      asm volatile("s_waitcnt vmcnt(0)" ::: "memory");
    }
    __builtin_amdgcn_s_barrier();
    MMA_Q(af47, bf01, 4, 0);
    __builtin_amdgcn_s_barrier();
  }
  // epilogue: final Qd of tile NT-1
  MMA_Q(af47, bf23, 4, 2);
#undef RD_A
#undef RD_B
#undef MMA_Q

  if constexpr (MODE == 1) {
#pragma unroll
    for (int m = 0; m < 8; ++m) {
#pragma unroll
      for (int n = 0; n < 4; ++n) {
        int col = bn + wc * 64 + n * 16 + l16;
#pragma unroll
        for (int r = 0; r < 4; ++r) {
          int row = bm + wr * 128 + m * 16 + lhi * 4 + r;
          C[(size_t)row * N + col] = acc[m][n][r];
        }
      }
    }
  } else {
    // MODE 2: fused QKV epilogue. part: 0=q, 1=k, 2=v (block-uniform).
    const int part = bn >> 11;
    const float kC = 0.08838834764831845f * 1.44269504088896340f;
    if (part < 2) {
      const float qs = (part == 0) ? kC : 1.0f;
      short* dst = (part == 0) ? Qr : Kr;
#pragma unroll
      for (int m = 0; m < 8; ++m) {
#pragma unroll
        for (int n = 0; n < 4; ++n) {
          int colm = (bn & 2047) + wc * 64 + n * 16 + l16;  // 0..2047
          int h = colm >> 7, d = colm & 127;
          int p2 = d >> 1;
          bool ev = (d & 1) == 0;
#pragma unroll
          for (int r = 0; r < 4; ++r) {
            int row = bm + wr * 128 + m * 16 + lhi * 4 + r;
            int b = row >> 11, t = row & 2047;
            float c = cosb[t * 64 + p2];
            float s = sinb[t * 64 + p2];
            float x = acc[m][n][r];
            float xp = __shfl_xor(x, 1);                    // partner d^1
            float y = ev ? (x * c - xp * s) : (xp * s + x * c);
            dst[((size_t)(b * 16 + h) * 2048 + t) * 128 + d] =
                (short)f2bf(y * qs);
          }
        }
      }
    } else {
#pragma unroll
      for (int m = 0; m < 8; ++m) {
#pragma unroll
        for (int n = 0; n < 4; ++n) {
          int colm = (bn & 2047) + wc * 64 + n * 16 + l16;
          int h = colm >> 7, d = colm & 127;
#pragma unroll
          for (int r = 0; r < 4; ++r) {
            int row = bm + wr * 128 + m * 16 + lhi * 4 + r;
            int b = row >> 11, t = row & 2047;
            VT[((size_t)(b * 16 + h) * 128 + d) * 2048 + t] =
                (short)f2bf(acc[m][n][r]);
          }
        }
      }
    }
  }
}

// ---------------- causal flash attention (round-2 v2 + T5, proven) --------
__global__ __launch_bounds__(256) void k_attn(const short* __restrict__ Qr,
                                              const short* __restrict__ Kr,
                                              const short* __restrict__ VT,
                                              short* __restrict__ Y) {
  __shared__ short sK[2][64 * 128];
  __shared__ short sVT[2][128 * 64];
  __shared__ short sP[4][16 * 64];
  const int tid = threadIdx.x, wv = tid >> 6, lane = tid & 63;
  const int l8r = lane >> 3, l8c = lane & 7, l16 = lane & 15, lhi = lane >> 4;
  const int bid = blockIdx.x;
  const int pair = bid & 15, bh = bid >> 4;
  const size_t base = (size_t)bh * 2048 * 128;
  const int b = bh >> 4, h = bh & 15;

  const short ob = (short)0x3F80;                   // bf16 1.0
  const bf16x8 ones = {ob, ob, ob, ob, ob, ob, ob, ob};

  auto stage = [&](int kv0, int buf) {
#pragma unroll
    for (int rr = 0; rr < 4; ++rr) {
      int ch = rr * 4 + wv;
      {                                    // sK: row stride 256B, chunk = 4 rows
        int row = ch * 4 + lhi;
        int wch = l16 ^ (row & 7);         // inverse-swizzled source chunk
        gld_lds16(Kr + base + (size_t)(kv0 + row) * 128 + wch * 8,
                  &sK[buf][ch * 512]);
      }
      {                                    // sVT: row stride 128B, chunk = 8 rows
        int drow = ch * 8 + l8r;
        int wch = l8c ^ (drow & 7);
        gld_lds16(VT + base + (size_t)drow * 2048 + kv0 + wch * 8,
                  &sVT[buf][ch * 512]);
      }
    }
  };

  for (int half = 0; half < 2; ++half) {
    const int qt = half ? 31 - pair : pair;
    const int q0 = qt * 64;
    const int nt = qt + 1;

    bf16x8 qf[4];
    const int qrow = q0 + wv * 16 + l16;
#pragma unroll
    for (int ks = 0; ks < 4; ++ks)
      qf[ks] = *reinterpret_cast<const bf16x8*>(Qr + base + (size_t)qrow * 128 +
                                                ks * 32 + lhi * 8);

    f32x4 acc_o[8] = {};
    f32x4 acc_l = {};
    float m_run[4];
#pragma unroll
    for (int r = 0; r < 4; ++r) m_run[r] = -1e30f;

    stage(0, 0);
    __syncthreads();

    for (int it = 0; it < nt; ++it) {
      const int cur = it & 1;
      if (it + 1 < nt) stage((it + 1) * 64, cur ^ 1);   // prefetch next tile

      // S = Q K^T  (scores already in exp2 domain: kC folded into Q)
      f32x4 sacc[4] = {};
      __builtin_amdgcn_s_setprio(1);
#pragma unroll
      for (int cf = 0; cf < 4; ++cf) {
        int krow = cf * 16 + l16;
#pragma unroll
        for (int ks = 0; ks < 4; ++ks) {
          int e = krow * 128 + ks * 32 + lhi * 8;
          bf16x8 kf = *reinterpret_cast<const bf16x8*>(
              &sK[cur][e ^ ((krow & 7) << 3)]);
          sacc[cf] = __builtin_amdgcn_mfma_f32_16x16x32_bf16(qf[ks], kf,
                                                             sacc[cf], 0, 0, 0);
        }
      }
      __builtin_amdgcn_s_setprio(0);

      if (it == nt - 1) {                  // causal mask on diagonal tile
#pragma unroll
        for (int cf = 0; cf < 4; ++cf) {
          int col = cf * 16 + l16;
#pragma unroll
          for (int r = 0; r < 4; ++r)
            if (col > wv * 16 + lhi * 4 + r) sacc[cf][r] = -3e38f;
        }
      }

      // defer-max: slow path only when a row max grows past THR=8 (exp2-units)
      bool exceed = false;
#pragma unroll
      for (int cf = 0; cf < 4; ++cf)
#pragma unroll
        for (int r = 0; r < 4; ++r)
          exceed |= (sacc[cf][r] > m_run[r] + 8.f);

      if (__any(exceed)) {
        float resc[4];
#pragma unroll
        for (int r = 0; r < 4; ++r) {
          float mx = fmaxf(fmaxf(sacc[0][r], sacc[1][r]),
                           fmaxf(sacc[2][r], sacc[3][r]));
          mx = fmaxf(mx, __shfl_xor(mx, 1));
          mx = fmaxf(mx, __shfl_xor(mx, 2));
          mx = fmaxf(mx, __shfl_xor(mx, 4));
          mx = fmaxf(mx, __shfl_xor(mx, 8));
          float mnew = fmaxf(m_run[r], mx);
          resc[r] = exp2f(m_run[r] - mnew);
          m_run[r] = mnew;
        }
#pragma unroll
        for (int df = 0; df < 8; ++df)
#pragma unroll
          for (int r = 0; r < 4; ++r) acc_o[df][r] *= resc[r];
#pragma unroll
        for (int r = 0; r < 4; ++r) acc_l[r] *= resc[r];
      }

      // P = exp2(S - m), bf16, into per-wave swizzled LDS (A-frag reshape)
#pragma unroll
      for (int cf = 0; cf < 4; ++cf)
#pragma unroll
        for (int r = 0; r < 4; ++r) {
          float p = exp2f(sacc[cf][r] - m_run[r]);
          int prow = lhi * 4 + r;
          int e = prow * 64 + cf * 16 + l16;
          sP[wv][e ^ ((prow & 7) << 3)] = (short)f2bf(p);
        }

      // O += P V ; l += P * ones  (row-sum via MFMA, no shuffle reduce)
      __builtin_amdgcn_s_setprio(1);
#pragma unroll
      for (int kk = 0; kk < 2; ++kk) {
        int e = l16 * 64 + kk * 32 + lhi * 8;
        bf16x8 pa = *reinterpret_cast<const bf16x8*>(
            &sP[wv][e ^ ((l16 & 7) << 3)]);
        acc_l = __builtin_amdgcn_mfma_f32_16x16x32_bf16(pa, ones, acc_l, 0, 0, 0);
#pragma unroll
        for (int df = 0; df < 8; ++df) {
          int vrow = df * 16 + l16;
          int ev = vrow * 64 + kk * 32 + lhi * 8;
          bf16x8 vb = *reinterpret_cast<const bf16x8*>(
              &sVT[cur][ev ^ ((vrow & 7) << 3)]);
          acc_o[df] = __builtin_amdgcn_mfma_f32_16x16x32_bf16(pa, vb,
                                                              acc_o[df], 0, 0, 0);
        }
      }
      __builtin_amdgcn_s_setprio(0);
      __syncthreads();   // drains prefetch vmcnt + protects LDS buffers
    }

    float inv[4];
#pragma unroll
    for (int r = 0; r < 4; ++r) inv[r] = 1.f / acc_l[r];
#pragma unroll
    for (int df = 0; df < 8; ++df) {
      int col = h * 128 + df * 16 + l16;
#pragma unroll
      for (int r = 0; r < 4; ++r) {
        int row = q0 + wv * 16 + lhi * 4 + r;
        Y[((size_t)b * 2048 + row) * 2048 + col] =
            (short)f2bf(acc_o[df][r] * inv[r]);
      }
    }
  }
}

// ---------------- launch ----------------
extern "C" void kernel_launch(void* const* d_in, const int* in_sizes, int n_in,
                              void* d_out, int out_size, void* d_ws, size_t ws_size,
                              hipStream_t stream) {
  const float* x        = (const float*)d_in[0];
  const float* w_attn   = (const float*)d_in[1];
  const float* w_proj   = (const float*)d_in[2];
  const float* rope_cos = (const float*)d_in[3];
  const float* rope_sin = (const float*)d_in[4];

  char* ws = (char*)d_ws;                     // 256 MiB total layout
  short* xbf    = (short*)(ws);               // 33.5 MB  [8192][2048]
  short* wattnT = (short*)(ws + 33554432ull); // 25.2 MB  [6144][2048]
  short* wprojT = (short*)(ws + 58720256ull); //  8.4 MB  [2048][2048]
  short* Y      = (short*)(ws + 67108864ull); // 33.5 MB  [8192][2048]
  short* Qr     = (short*)(ws + 167772160ull);// 33.5 MB  [B,H,T,128]
  short* Kr     = (short*)(ws + 201326592ull);// 33.5 MB  [B,H,T,128]
  short* VT     = (short*)(ws + 234881024ull);// 33.5 MB  [B,H,128,T]

  k_prep<<<20480, 256, 0, stream>>>(x, xbf, w_attn, wattnT, w_proj, wprojT);
  k_gemm10<2, short><<<dim3(32, 24), 512, 0, stream>>>(
      xbf, wattnT, (short*)nullptr, 8192, 6144, 2048,
      rope_cos, rope_sin, Qr, Kr, VT);
  k_attn<<<1024, 256, 0, stream>>>(Qr, Kr, VT, Y);
  k_gemm10<1, float><<<dim3(32, 8), 512, 0, stream>>>(
      Y, wprojT, (float*)d_out, 8192, 2048, 2048,
      nullptr, nullptr, nullptr, nullptr, nullptr);
}

// Round 15
// 440.128 us; speedup vs baseline: 1.1156x; 1.0549x over previous
//
#include <hip/hip_runtime.h>
#include <cstdint>
#include <cstddef>

#define DEVI __device__ __forceinline__

typedef __attribute__((ext_vector_type(8))) short bf16x8;
typedef __attribute__((ext_vector_type(4))) float f32x4;

DEVI unsigned short f2bf(float f) {
  unsigned int u = __float_as_uint(f);
  u += 0x7fffu + ((u >> 16) & 1u);   // RNE
  return (unsigned short)(u >> 16);
}
DEVI float bf2f(unsigned int us) { return __uint_as_float(us << 16); }

DEVI void gld_lds16(const void* g, void* l) {
  __builtin_amdgcn_global_load_lds(
      (const __attribute__((address_space(1))) void*)g,
      (__attribute__((address_space(3))) void*)l, 16, 0, 0);
}

// ---------------- fused prep: x->bf16 conv + both weight transposes -------
__global__ __launch_bounds__(256) void k_prep(const float* __restrict__ x,
                                              short* __restrict__ xbf,
                                              const float* __restrict__ w_attn,
                                              short* __restrict__ wattnT,
                                              const float* __restrict__ w_proj,
                                              short* __restrict__ wprojT) {
  const int bid = blockIdx.x, tid = threadIdx.x;
  if (bid < 16384) {
    int i = bid * 256 + tid;
    float4 v = reinterpret_cast<const float4*>(x)[i];
    uint2 o;
    o.x = (unsigned)f2bf(v.x) | ((unsigned)f2bf(v.y) << 16);
    o.y = (unsigned)f2bf(v.z) | ((unsigned)f2bf(v.w) << 16);
    reinterpret_cast<uint2*>(xbf)[i] = o;
    return;
  }
  __shared__ short tile[64][66];
  const float* in;
  short* out;
  int R, Cc, tb, rb;
  if (bid < 19456) {
    in = w_attn; out = wattnT; R = 2048; Cc = 6144;
    int t = bid - 16384; tb = t % 96; rb = t / 96;
  } else {
    in = w_proj; out = wprojT; R = 2048; Cc = 2048;
    int t = bid - 19456; tb = t % 32; rb = t / 32;
  }
#pragma unroll
  for (int rep = 0; rep < 16; ++rep) {
    int idx = rep * 256 + tid;
    int r = idx >> 6, c = idx & 63;
    tile[r][c] = (short)f2bf(in[(size_t)(rb * 64 + r) * Cc + tb * 64 + c]);
  }
  __syncthreads();
#pragma unroll
  for (int rep = 0; rep < 16; ++rep) {
    int idx = rep * 256 + tid;
    int r = idx >> 6, c = idx & 63;
    out[(size_t)(tb * 64 + r) * R + rb * 64 + c] = tile[c][r];
  }
}

// ---------------- bf16 GEMM: 4-phase/K-tile, unpinned (round-14, frozen) --
// BM=BN=256, BK=64, 512 thr (8 waves 2Mx4N), 2 LDS bufs (128KB).
// MODE 1: plain fp32 C.  MODE 2: fused QKV epilogue (RoPE'd Q,K + V^T).
template <int MODE, typename OutT>
__global__ __launch_bounds__(512, 2) void k_gemm10(const short* __restrict__ A,
                                                   const short* __restrict__ BT,
                                                   OutT* __restrict__ C,
                                                   int M, int N, int K,
                                                   const float* __restrict__ cosb,
                                                   const float* __restrict__ sinb,
                                                   short* __restrict__ Qr,
                                                   short* __restrict__ Kr,
                                                   short* __restrict__ VT) {
  __shared__ short sA[2][256 * 64];
  __shared__ short sB[2][256 * 64];
  const int tid = threadIdx.x;
  const int wv = tid >> 6, lane = tid & 63;
  const int l16 = lane & 15, lhi = lane >> 4;
  const int wr = wv >> 2, wc = wv & 3;          // wave grid 2M x 4N
  const int bm = blockIdx.x * 256, bn = blockIdx.y * 256;
  const int NT = K >> 6;                        // BK=64 tiles
  const int lr8 = lane >> 3, lg8 = lane & 7;

  auto stageA = [&](int half, int kt, int b) {
#pragma unroll
    for (int j = 0; j < 2; ++j) {
      int row0 = j * 128 + wv * 8 + half * 64;
      int row = row0 + lr8;
      int g = lg8 ^ lr8;
      gld_lds16(A + (size_t)(bm + row) * K + kt + g * 8, &sA[b][row0 * 64]);
    }
  };
  auto stageB = [&](int half, int kt, int b) {
#pragma unroll
    for (int j = 0; j < 2; ++j) {
      int ri0 = j * 64 + wv * 8;
      int row0 = (ri0 >> 5) * 64 + half * 32 + (ri0 & 31);
      int row = row0 + lr8;
      int g = lg8 ^ lr8;
      gld_lds16(BT + (size_t)(bn + row) * K + kt + g * 8, &sB[b][row0 * 64]);
    }
  };

  f32x4 acc[8][4] = {};
  bf16x8 af03[4][2], af47[4][2], bf01[2][2], bf23[2][2];

#define RD_A(DST, MB, BUF)                                                     \
  _Pragma("unroll") for (int m = 0; m < 4; ++m)                                \
      _Pragma("unroll") for (int ks = 0; ks < 2; ++ks) {                       \
    int row = wr * 128 + ((MB) + m) * 16 + l16;                                \
    DST[m][ks] = *(const bf16x8*)&(BUF)[row * 64 +                             \
                                        (((ks * 4 + lhi) ^ (row & 7)) << 3)];  \
  }
#define RD_B(DST, NB, BUF)                                                     \
  _Pragma("unroll") for (int n = 0; n < 2; ++n)                                \
      _Pragma("unroll") for (int ks = 0; ks < 2; ++ks) {                       \
    int row = wc * 64 + ((NB) + n) * 16 + l16;                                 \
    DST[n][ks] = *(const bf16x8*)&(BUF)[row * 64 +                             \
                                        (((ks * 4 + lhi) ^ (row & 7)) << 3)];  \
  }
#define MMA_Q(AF, BF, MO, NO)                                                  \
  __builtin_amdgcn_s_setprio(1);                                               \
  _Pragma("unroll") for (int m = 0; m < 4; ++m)                                \
      _Pragma("unroll") for (int n = 0; n < 2; ++n)                            \
          _Pragma("unroll") for (int ks = 0; ks < 2; ++ks)                     \
              acc[(MO) + m][(NO) + n] = __builtin_amdgcn_mfma_f32_16x16x32_bf16(\
                  AF[m][ks], BF[n][ks], acc[(MO) + m][(NO) + n], 0, 0, 0);     \
  __builtin_amdgcn_s_setprio(0);

  // prologue: stage tile 0's 4 halves, drain, publish
  stageA(0, 0, 0); stageB(0, 0, 0); stageB(1, 0, 0); stageA(1, 0, 0);
  asm volatile("s_waitcnt vmcnt(0)" ::: "memory");
  __builtin_amdgcn_s_barrier();

  for (int t = 0; t < NT; ++t) {
    const int cur = t & 1, nxt = cur ^ 1;
    const int kt1 = (t + 1) * 64;
    const bool pf = (t + 1 < NT);
    const short* bufA = sA[cur];
    const short* bufB = sB[cur];
    // ---- P0: read af m0-3 | stage A-half0(t+1) | MFMA Qd of t-1 ----
    RD_A(af03, 0, bufA);
    if (pf) stageA(0, kt1, nxt);
    __builtin_amdgcn_s_barrier();
    if (t) { MMA_Q(af47, bf23, 4, 2); }
    __builtin_amdgcn_s_barrier();
    // ---- P1: read bf n0-1 | stage B-half0 | gate | MFMA Qa ----
    RD_B(bf01, 0, bufB);
    if (pf) {
      stageB(0, kt1, nxt);
      asm volatile("s_waitcnt vmcnt(4)" ::: "memory");   // t's B1,A1 landed
    } else {
      asm volatile("s_waitcnt vmcnt(0)" ::: "memory");
    }
    __builtin_amdgcn_s_barrier();
    MMA_Q(af03, bf01, 0, 0);
    __builtin_amdgcn_s_barrier();
    // ---- P2: read bf n2-3 | stage B-half1 | MFMA Qb ----
    RD_B(bf23, 2, bufB);
    if (pf) stageB(1, kt1, nxt);
    __builtin_amdgcn_s_barrier();
    MMA_Q(af03, bf23, 0, 2);
    __builtin_amdgcn_s_barrier();
    // ---- P3: read af m4-7 | stage A-half1 | gate | MFMA Qc ----
    RD_A(af47, 4, bufA);
    if (pf) {
      stageA(1, kt1, nxt);
      asm volatile("s_waitcnt vmcnt(4)" ::: "memory");   // t+1's A0,B0 landed
    } else {
      asm volatile("s_waitcnt vmcnt(0)" ::: "memory");
    }
    __builtin_amdgcn_s_barrier();
    MMA_Q(af47, bf01, 4, 0);
    __builtin_amdgcn_s_barrier();
  }
  // epilogue: final Qd of tile NT-1
  MMA_Q(af47, bf23, 4, 2);
#undef RD_A
#undef RD_B
#undef MMA_Q

  if constexpr (MODE == 1) {
#pragma unroll
    for (int m = 0; m < 8; ++m) {
#pragma unroll
      for (int n = 0; n < 4; ++n) {
        int col = bn + wc * 64 + n * 16 + l16;
#pragma unroll
        for (int r = 0; r < 4; ++r) {
          int row = bm + wr * 128 + m * 16 + lhi * 4 + r;
          C[(size_t)row * N + col] = acc[m][n][r];
        }
      }
    }
  } else {
    // MODE 2: fused QKV epilogue. part: 0=q, 1=k, 2=v (block-uniform).
    const int part = bn >> 11;
    const float kC = 0.08838834764831845f * 1.44269504088896340f;
    if (part < 2) {
      const float qs = (part == 0) ? kC : 1.0f;
      short* dst = (part == 0) ? Qr : Kr;
#pragma unroll
      for (int m = 0; m < 8; ++m) {
#pragma unroll
        for (int n = 0; n < 4; ++n) {
          int colm = (bn & 2047) + wc * 64 + n * 16 + l16;  // 0..2047
          int h = colm >> 7, d = colm & 127;
          int p2 = d >> 1;
          bool ev = (d & 1) == 0;
#pragma unroll
          for (int r = 0; r < 4; ++r) {
            int row = bm + wr * 128 + m * 16 + lhi * 4 + r;
            int b = row >> 11, t = row & 2047;
            float c = cosb[t * 64 + p2];
            float s = sinb[t * 64 + p2];
            float x = acc[m][n][r];
            float xp = __shfl_xor(x, 1);                    // partner d^1
            float y = ev ? (x * c - xp * s) : (xp * s + x * c);
            dst[((size_t)(b * 16 + h) * 2048 + t) * 128 + d] =
                (short)f2bf(y * qs);
          }
        }
      }
    } else {
#pragma unroll
      for (int m = 0; m < 8; ++m) {
#pragma unroll
        for (int n = 0; n < 4; ++n) {
          int colm = (bn & 2047) + wc * 64 + n * 16 + l16;
          int h = colm >> 7, d = colm & 127;
#pragma unroll
          for (int r = 0; r < 4; ++r) {
            int row = bm + wr * 128 + m * 16 + lhi * 4 + r;
            int b = row >> 11, t = row & 2047;
            VT[((size_t)(b * 16 + h) * 128 + d) * 2048 + t] =
                (short)f2bf(acc[m][n][r]);
          }
        }
      }
    }
  }
}

// ---------------- causal flash attention (round-2 v2 + T5 + XCD remap) ----
// Logical block = (bh, pair): q-tiles qt=pair and 31-pair -> 33 KV iters.
// XCD-aware bid remap: all 16 pair-blocks of one bh get bids == bh (mod 8)
// -> same XCD (HW round-robins bid%8) -> that bh's 1MB K/V is fetched once
// per XCD and stays L2-resident; staging prefetch then completes from L2
// (~200cy) instead of HBM (~900cy) within the ~1100cy iteration window.
// bid = (bh>>3)*128 + pair*8 + (bh&7)  (bijective on [0,1024)).
__global__ __launch_bounds__(256) void k_attn(const short* __restrict__ Qr,
                                              const short* __restrict__ Kr,
                                              const short* __restrict__ VT,
                                              short* __restrict__ Y) {
  __shared__ short sK[2][64 * 128];
  __shared__ short sVT[2][128 * 64];
  __shared__ short sP[4][16 * 64];
  const int tid = threadIdx.x, wv = tid >> 6, lane = tid & 63;
  const int l8r = lane >> 3, l8c = lane & 7, l16 = lane & 15, lhi = lane >> 4;
  const int bid = blockIdx.x;
  const int pair = (bid >> 3) & 15;                 // inverse of the remap
  const int bh = ((bid >> 7) << 3) | (bid & 7);
  const size_t base = (size_t)bh * 2048 * 128;
  const int b = bh >> 4, h = bh & 15;

  const short ob = (short)0x3F80;                   // bf16 1.0
  const bf16x8 ones = {ob, ob, ob, ob, ob, ob, ob, ob};

  auto stage = [&](int kv0, int buf) {
#pragma unroll
    for (int rr = 0; rr < 4; ++rr) {
      int ch = rr * 4 + wv;
      {                                    // sK: row stride 256B, chunk = 4 rows
        int row = ch * 4 + lhi;
        int wch = l16 ^ (row & 7);         // inverse-swizzled source chunk
        gld_lds16(Kr + base + (size_t)(kv0 + row) * 128 + wch * 8,
                  &sK[buf][ch * 512]);
      }
      {                                    // sVT: row stride 128B, chunk = 8 rows
        int drow = ch * 8 + l8r;
        int wch = l8c ^ (drow & 7);
        gld_lds16(VT + base + (size_t)drow * 2048 + kv0 + wch * 8,
                  &sVT[buf][ch * 512]);
      }
    }
  };

  for (int half = 0; half < 2; ++half) {
    const int qt = half ? 31 - pair : pair;
    const int q0 = qt * 64;
    const int nt = qt + 1;

    bf16x8 qf[4];
    const int qrow = q0 + wv * 16 + l16;
#pragma unroll
    for (int ks = 0; ks < 4; ++ks)
      qf[ks] = *reinterpret_cast<const bf16x8*>(Qr + base + (size_t)qrow * 128 +
                                                ks * 32 + lhi * 8);

    f32x4 acc_o[8] = {};
    f32x4 acc_l = {};
    float m_run[4];
#pragma unroll
    for (int r = 0; r < 4; ++r) m_run[r] = -1e30f;

    stage(0, 0);
    __syncthreads();

    for (int it = 0; it < nt; ++it) {
      const int cur = it & 1;
      if (it + 1 < nt) stage((it + 1) * 64, cur ^ 1);   // prefetch next tile

      // S = Q K^T  (scores already in exp2 domain: kC folded into Q)
      f32x4 sacc[4] = {};
      __builtin_amdgcn_s_setprio(1);
#pragma unroll
      for (int cf = 0; cf < 4; ++cf) {
        int krow = cf * 16 + l16;
#pragma unroll
        for (int ks = 0; ks < 4; ++ks) {
          int e = krow * 128 + ks * 32 + lhi * 8;
          bf16x8 kf = *reinterpret_cast<const bf16x8*>(
              &sK[cur][e ^ ((krow & 7) << 3)]);
          sacc[cf] = __builtin_amdgcn_mfma_f32_16x16x32_bf16(qf[ks], kf,
                                                             sacc[cf], 0, 0, 0);
        }
      }
      __builtin_amdgcn_s_setprio(0);

      if (it == nt - 1) {                  // causal mask on diagonal tile
#pragma unroll
        for (int cf = 0; cf < 4; ++cf) {
          int col = cf * 16 + l16;
#pragma unroll
          for (int r = 0; r < 4; ++r)
            if (col > wv * 16 + lhi * 4 + r) sacc[cf][r] = -3e38f;
        }
      }

      // defer-max: slow path only when a row max grows past THR=8 (exp2-units)
      bool exceed = false;
#pragma unroll
      for (int cf = 0; cf < 4; ++cf)
#pragma unroll
        for (int r = 0; r < 4; ++r)
          exceed |= (sacc[cf][r] > m_run[r] + 8.f);

      if (__any(exceed)) {
        float resc[4];
#pragma unroll
        for (int r = 0; r < 4; ++r) {
          float mx = fmaxf(fmaxf(sacc[0][r], sacc[1][r]),
                           fmaxf(sacc[2][r], sacc[3][r]));
          mx = fmaxf(mx, __shfl_xor(mx, 1));
          mx = fmaxf(mx, __shfl_xor(mx, 2));
          mx = fmaxf(mx, __shfl_xor(mx, 4));
          mx = fmaxf(mx, __shfl_xor(mx, 8));
          float mnew = fmaxf(m_run[r], mx);
          resc[r] = exp2f(m_run[r] - mnew);
          m_run[r] = mnew;
        }
#pragma unroll
        for (int df = 0; df < 8; ++df)
#pragma unroll
          for (int r = 0; r < 4; ++r) acc_o[df][r] *= resc[r];
#pragma unroll
        for (int r = 0; r < 4; ++r) acc_l[r] *= resc[r];
      }

      // P = exp2(S - m), bf16, into per-wave swizzled LDS (A-frag reshape)
#pragma unroll
      for (int cf = 0; cf < 4; ++cf)
#pragma unroll
        for (int r = 0; r < 4; ++r) {
          float p = exp2f(sacc[cf][r] - m_run[r]);
          int prow = lhi * 4 + r;
          int e = prow * 64 + cf * 16 + l16;
          sP[wv][e ^ ((prow & 7) << 3)] = (short)f2bf(p);
        }

      // O += P V ; l += P * ones  (row-sum via MFMA, no shuffle reduce)
      __builtin_amdgcn_s_setprio(1);
#pragma unroll
      for (int kk = 0; kk < 2; ++kk) {
        int e = l16 * 64 + kk * 32 + lhi * 8;
        bf16x8 pa = *reinterpret_cast<const bf16x8*>(
            &sP[wv][e ^ ((l16 & 7) << 3)]);
        acc_l = __builtin_amdgcn_mfma_f32_16x16x32_bf16(pa, ones, acc_l, 0, 0, 0);
#pragma unroll
        for (int df = 0; df < 8; ++df) {
          int vrow = df * 16 + l16;
          int ev = vrow * 64 + kk * 32 + lhi * 8;
          bf16x8 vb = *reinterpret_cast<const bf16x8*>(
              &sVT[cur][ev ^ ((vrow & 7) << 3)]);
          acc_o[df] = __builtin_amdgcn_mfma_f32_16x16x32_bf16(pa, vb,
                                                              acc_o[df], 0, 0, 0);
        }
      }
      __builtin_amdgcn_s_setprio(0);
      __syncthreads();   // drains prefetch vmcnt + protects LDS buffers
    }

    float inv[4];
#pragma unroll
    for (int r = 0; r < 4; ++r) inv[r] = 1.f / acc_l[r];
#pragma unroll
    for (int df = 0; df < 8; ++df) {
      int col = h * 128 + df * 16 + l16;
#pragma unroll
      for (int r = 0; r < 4; ++r) {
        int row = q0 + wv * 16 + lhi * 4 + r;
        Y[((size_t)b * 2048 + row) * 2048 + col] =
            (short)f2bf(acc_o[df][r] * inv[r]);
      }
    }
  }
}

// ---------------- launch ----------------
extern "C" void kernel_launch(void* const* d_in, const int* in_sizes, int n_in,
                              void* d_out, int out_size, void* d_ws, size_t ws_size,
                              hipStream_t stream) {
  const float* x        = (const float*)d_in[0];
  const float* w_attn   = (const float*)d_in[1];
  const float* w_proj   = (const float*)d_in[2];
  const float* rope_cos = (const float*)d_in[3];
  const float* rope_sin = (const float*)d_in[4];

  char* ws = (char*)d_ws;                     // 256 MiB total layout
  short* xbf    = (short*)(ws);               // 33.5 MB  [8192][2048]
  short* wattnT = (short*)(ws + 33554432ull); // 25.2 MB  [6144][2048]
  short* wprojT = (short*)(ws + 58720256ull); //  8.4 MB  [2048][2048]
  short* Y      = (short*)(ws + 67108864ull); // 33.5 MB  [8192][2048]
  short* Qr     = (short*)(ws + 167772160ull);// 33.5 MB  [B,H,T,128]
  short* Kr     = (short*)(ws + 201326592ull);// 33.5 MB  [B,H,T,128]
  short* VT     = (short*)(ws + 234881024ull);// 33.5 MB  [B,H,128,T]

  k_prep<<<20480, 256, 0, stream>>>(x, xbf, w_attn, wattnT, w_proj, wprojT);
  k_gemm10<2, short><<<dim3(32, 24), 512, 0, stream>>>(
      xbf, wattnT, (short*)nullptr, 8192, 6144, 2048,
      rope_cos, rope_sin, Qr, Kr, VT);
  k_attn<<<1024, 256, 0, stream>>>(Qr, Kr, VT, Y);
  k_gemm10<1, float><<<dim3(32, 8), 512, 0, stream>>>(
      Y, wprojT, (float*)d_out, 8192, 2048, 2048,
      nullptr, nullptr, nullptr, nullptr, nullptr);
}